// Round 18
// baseline (108.885 us; speedup 1.0000x reference)
//
#include <hip/hip_runtime.h>
#include <hip/hip_cooperative_groups.h>

namespace cg = cooperative_groups;

#define BATCH 256
#define ZTILE 16          // z per LDS tile (16 tiles total)
#define YSPLIT 3          // fallback path tile stride
#define PADF 20           // floats per stripe (16 z + 4 pad) = 80 B
#define DIN_CAP 416       // dim_in for this problem

// Barrier that waits only on LDS ops, leaving global stores in flight.
__device__ __forceinline__ void lds_sync()
{
    asm volatile("s_waitcnt lgkmcnt(0)" ::: "memory");
    __builtin_amdgcn_sched_barrier(0);
    __builtin_amdgcn_s_barrier();
    __builtin_amdgcn_sched_barrier(0);
}

// Fused cooperative kernel; ALL phases grid-stride so any grid size is correct.
__global__ __launch_bounds__(256) void tsq_fused(
    const float* __restrict__ f, const float* __restrict__ vals,
    const int* __restrict__ ci, const int* __restrict__ cj,
    const int* __restrict__ rows, int* __restrict__ rstart,
    int* __restrict__ rend, float* __restrict__ fT,
    float* __restrict__ out,
    int nnz, int dim_in, int dim_out, int TB, int ctiles, int nxblk)
{
    __shared__ __align__(16) char smem[DIN_CAP * PADF * 4];   // 33280 B

    const int tid = threadIdx.x;
    const int b   = blockIdx.x;
    const int G   = gridDim.x;

    // ---- Phase A1: tiled transpose f -> fT (grid-stride over TB tiles)
    {
        float (*lt)[33] = (float (*)[33])smem;
        for (int w = b; w < TB; w += G) {
            const int c0 = (w % ctiles) * 32;
            const int z0 = (w / ctiles) * 32;
            const int ic = tid & 31;
            const int i0 = tid >> 5;
#pragma unroll
            for (int k = 0; k < 4; ++k) {
                const int a = i0 + 8 * k;
                const int c = c0 + ic;
                lt[a][ic] = (c < dim_in) ? f[(size_t)(z0 + a) * dim_in + c] : 0.0f;
            }
            __syncthreads();
#pragma unroll
            for (int k = 0; k < 4; ++k) {
                const int bb = i0 + 8 * k;
                const int c  = c0 + bb;
                if (c < dim_in)
                    fT[(size_t)c * BATCH + z0 + ic] = lt[ic][bb];
            }
            __syncthreads();
        }
    }
    // ---- Phase A2: bounds scatter (grid-stride; consumer rejects poison)
    for (int e = b * 256 + tid; e < nnz; e += G * 256) {
        const int rr = rows[e];
        if (e == 0 || rows[e - 1] != rr) rstart[rr] = e;
        if (e == nnz - 1 || rows[e + 1] != rr) rend[rr] = e + 1;
    }

    cg::this_grid().sync();   // fT + bounds visible device-wide

    // ---- Phase B: grid-stride over (row-block, z-tile) work units
    float* fzT = (float*)smem;
    const int nchunk = dim_in * (ZTILE / 4);
    const int ntile  = BATCH / ZTILE;          // 16
    const int nwork  = nxblk * ntile;

    for (int w = b; w < nwork; w += G) {
        const int xb = w % nxblk;
        const int t  = w / nxblk;
        const int z0 = t * ZTILE;
        const int r  = xb * 256 + tid;
        const bool valid = (r < dim_out);

        int s = 0, e1 = 0;
        if (valid) {
            const int ss = rstart[r];
            const int ee = rend[r];
            if (ss >= 0 && ee > ss && ee <= nnz) { s = ss; e1 = ee; }
        }

        for (int i = tid; i < nchunk; i += 256) {
            const int c  = i >> 2;
            const int zq = i & 3;
            const float4 v = *(const float4*)(fT + (size_t)c * BATCH + z0 + zq * 4);
            *(float4*)(fzT + c * PADF + zq * 4) = v;
        }
        lds_sync();

        float4 a0 = {0,0,0,0}, a1 = {0,0,0,0}, a2 = {0,0,0,0}, a3 = {0,0,0,0};
        for (int e = s; e < e1; ++e) {
            const int   a  = ci[e];
            const int   bb = cj[e];
            const float v  = vals[e];
            const float* ba = fzT + a * PADF;
            const float* bc = fzT + bb * PADF;
            float4 xa, xb;
            xa = *(const float4*)(ba);      xb = *(const float4*)(bc);
            a0.x += v*xa.x*xb.x; a0.y += v*xa.y*xb.y; a0.z += v*xa.z*xb.z; a0.w += v*xa.w*xb.w;
            xa = *(const float4*)(ba + 4);  xb = *(const float4*)(bc + 4);
            a1.x += v*xa.x*xb.x; a1.y += v*xa.y*xb.y; a1.z += v*xa.z*xb.z; a1.w += v*xa.w*xb.w;
            xa = *(const float4*)(ba + 8);  xb = *(const float4*)(bc + 8);
            a2.x += v*xa.x*xb.x; a2.y += v*xa.y*xb.y; a2.z += v*xa.z*xb.z; a2.w += v*xa.w*xb.w;
            xa = *(const float4*)(ba + 12); xb = *(const float4*)(bc + 12);
            a3.x += v*xa.x*xb.x; a3.y += v*xa.y*xb.y; a3.z += v*xa.z*xb.z; a3.w += v*xa.w*xb.w;
        }

        if (valid) {
            float* o = out + (size_t)z0 * dim_out + r;
            const size_t d = dim_out;
            o[0]    = a0.x;  o[d]    = a0.y;  o[2*d]  = a0.z;  o[3*d]  = a0.w;
            o[4*d]  = a1.x;  o[5*d]  = a1.y;  o[6*d]  = a1.z;  o[7*d]  = a1.w;
            o[8*d]  = a2.x;  o[9*d]  = a2.y;  o[10*d] = a2.z;  o[11*d] = a2.w;
            o[12*d] = a3.x;  o[13*d] = a3.y;  o[14*d] = a3.z;  o[15*d] = a3.w;
        }
        lds_sync();
    }
}

// ---------------- proven R15 two-kernel fallback path ----------------
__global__ __launch_bounds__(256) void prep_t(
    const float* __restrict__ f, const int* __restrict__ rows,
    int* __restrict__ rstart, int* __restrict__ rend,
    float* __restrict__ fT, int nnz, int dim_in, int TB, int ctiles)
{
    const int bx = blockIdx.x;
    if (bx < TB) {
        __shared__ float lt[32][33];
        const int c0 = (bx % ctiles) * 32;
        const int z0 = (bx / ctiles) * 32;
        const int ic = threadIdx.x & 31;
        const int i0 = threadIdx.x >> 5;
#pragma unroll
        for (int k = 0; k < 4; ++k) {
            const int a = i0 + 8 * k;
            const int c = c0 + ic;
            lt[a][ic] = (c < dim_in) ? f[(size_t)(z0 + a) * dim_in + c] : 0.0f;
        }
        __syncthreads();
#pragma unroll
        for (int k = 0; k < 4; ++k) {
            const int bb = i0 + 8 * k;
            const int c  = c0 + bb;
            if (c < dim_in)
                fT[(size_t)c * BATCH + z0 + ic] = lt[ic][bb];
        }
    } else {
        const int e = (bx - TB) * 256 + threadIdx.x;
        if (e < nnz) {
            const int r = rows[e];
            if (e == 0 || rows[e - 1] != r) rstart[r] = e;
            if (e == nnz - 1 || rows[e + 1] != r) rend[r] = e + 1;
        }
    }
}

__global__ __launch_bounds__(256) void tsq_main(
    const float* __restrict__ fT, const float* __restrict__ vals,
    const int* __restrict__ ci, const int* __restrict__ cj,
    const int* __restrict__ rstart, const int* __restrict__ rend,
    float* __restrict__ out, int dim_in, int dim_out, int nnz)
{
    __shared__ __align__(16) float fzT[DIN_CAP * PADF];

    const int r = blockIdx.x * 256 + threadIdx.x;
    const bool valid = (r < dim_out);

    int s = 0, e1 = 0;
    if (valid) {
        const int ss = rstart[r];
        const int ee = rend[r];
        if (ss >= 0 && ee > ss && ee <= nnz) { s = ss; e1 = ee; }
    }

    const int nchunk = dim_in * (ZTILE / 4);
    for (int t = blockIdx.y; t < BATCH / ZTILE; t += YSPLIT) {
        const int z0 = t * ZTILE;
        for (int i = threadIdx.x; i < nchunk; i += 256) {
            const int c  = i >> 2;
            const int zq = i & 3;
            const float4 v = *(const float4*)(fT + (size_t)c * BATCH + z0 + zq * 4);
            *(float4*)(fzT + c * PADF + zq * 4) = v;
        }
        lds_sync();

        float4 a0 = {0,0,0,0}, a1 = {0,0,0,0}, a2 = {0,0,0,0}, a3 = {0,0,0,0};
        for (int e = s; e < e1; ++e) {
            const int   a  = ci[e];
            const int   bb = cj[e];
            const float v  = vals[e];
            const float* ba = fzT + a * PADF;
            const float* bc = fzT + bb * PADF;
            float4 xa, xb;
            xa = *(const float4*)(ba);      xb = *(const float4*)(bc);
            a0.x += v*xa.x*xb.x; a0.y += v*xa.y*xb.y; a0.z += v*xa.z*xb.z; a0.w += v*xa.w*xb.w;
            xa = *(const float4*)(ba + 4);  xb = *(const float4*)(bc + 4);
            a1.x += v*xa.x*xb.x; a1.y += v*xa.y*xb.y; a1.z += v*xa.z*xb.z; a1.w += v*xa.w*xb.w;
            xa = *(const float4*)(ba + 8);  xb = *(const float4*)(bc + 8);
            a2.x += v*xa.x*xb.x; a2.y += v*xa.y*xb.y; a2.z += v*xa.z*xb.z; a2.w += v*xa.w*xb.w;
            xa = *(const float4*)(ba + 12); xb = *(const float4*)(bc + 12);
            a3.x += v*xa.x*xb.x; a3.y += v*xa.y*xb.y; a3.z += v*xa.z*xb.z; a3.w += v*xa.w*xb.w;
        }

        if (valid) {
            float* o = out + (size_t)z0 * dim_out + r;
            const size_t d = dim_out;
            o[0]    = a0.x;  o[d]    = a0.y;  o[2*d]  = a0.z;  o[3*d]  = a0.w;
            o[4*d]  = a1.x;  o[5*d]  = a1.y;  o[6*d]  = a1.z;  o[7*d]  = a1.w;
            o[8*d]  = a2.x;  o[9*d]  = a2.y;  o[10*d] = a2.z;  o[11*d] = a2.w;
            o[12*d] = a3.x;  o[13*d] = a3.y;  o[14*d] = a3.z;  o[15*d] = a3.w;
        }
        lds_sync();
    }
}

extern "C" void kernel_launch(void* const* d_in, const int* in_sizes, int n_in,
                              void* d_out, int out_size, void* d_ws, size_t ws_size,
                              hipStream_t stream)
{
    const float* f    = (const float*)d_in[0];
    const float* vals = (const float*)d_in[1];
    const int*   rows = (const int*)d_in[2];
    const int*   ci   = (const int*)d_in[3];
    const int*   cj   = (const int*)d_in[4];
    float*       out  = (float*)d_out;

    const int nnz     = in_sizes[1];
    const int nF      = in_sizes[0];
    const int dim_in  = nF / BATCH;
    const int dim_out = out_size / BATCH;

    int*   rstart = (int*)d_ws;
    int*   rend   = rstart + dim_out;
    float* fT     = (float*)(rend + dim_out);

    const int ctiles = (dim_in + 31) / 32;
    const int TB     = ctiles * (BATCH / 32);
    const int nxblk  = (dim_out + 255) / 256;

    const bool ws_ok = (dim_in <= DIN_CAP) &&
        (ws_size >= (size_t)(2 * dim_out) * 4 + (size_t)nF * 4);

    bool launched = false;
    if (ws_ok) {
        // measured co-residency capacity (R16 failed by assuming it)
        int maxb = 0;
        hipError_t oe = hipOccupancyMaxActiveBlocksPerMultiprocessor(
            &maxb, tsq_fused, 256, 0);
        int numCU = 0;
        hipDeviceGetAttribute(&numCU, hipDeviceAttributeMultiprocessorCount, 0);
        if (oe == hipSuccess && maxb > 0 && numCU > 0) {
            int G = maxb * numCU;
            const int nwork = nxblk * (BATCH / ZTILE);
            if (G > nwork) G = nwork;
            void* args[] = {
                (void*)&f, (void*)&vals, (void*)&ci, (void*)&cj, (void*)&rows,
                (void*)&rstart, (void*)&rend, (void*)&fT, (void*)&out,
                (void*)&nnz, (void*)&dim_in, (void*)&dim_out,
                (void*)&TB, (void*)&ctiles, (void*)&nxblk };
            launched = (hipLaunchCooperativeKernel((const void*)tsq_fused,
                        dim3(G), dim3(256), args, 0, stream) == hipSuccess);
        }
    }

    if (!launched && ws_ok) {   // proven R15 path
        const int NB = (nnz + 255) / 256;
        prep_t<<<TB + NB, 256, 0, stream>>>(f, rows, rstart, rend, fT,
                                            nnz, dim_in, TB, ctiles);
        dim3 grid(nxblk, YSPLIT);
        tsq_main<<<grid, 256, 0, stream>>>(fT, vals, ci, cj, rstart, rend, out,
                                           dim_in, dim_out, nnz);
    }
}